// Round 13
// baseline (8040.436 us; speedup 1.0000x reference)
//
#include <hip/hip_runtime.h>

typedef float floatx4 __attribute__((ext_vector_type(4)));
typedef _Float16 f16x8 __attribute__((ext_vector_type(8)));

#define D0_ 19
#define H0_ 200
#define W0_ 176
#define HW_ (H0_*W0_)          // 35200
#define NCELL0 (D0_*HW_)       // 668800
#define D1_ 9
#define NCELL1 (D1_*HW_)       // 316800
#define D2_ 4
#define NCELL2 (D2_*HW_)       // 140800
#define NV_ 40000
#define CAP0 40000
#define CAP1 80000
#define CAP2 140800
#define EPS_ 1e-3f

__device__ __forceinline__ short f2h(float f){
    _Float16 h = (_Float16)f;
    short s; __builtin_memcpy(&s, &h, 2); return s;
}

// ---------------- fused constant prep: BN consts + 5 weight repacks (fp16) ----------------
__device__ __forceinline__ void repack_one(const float* w, short* Bout, int i,
                                           int KCsrc, int kshift, int NSP){
    int k = i >> 6, n = i & 63;
    int j = k >> kshift;
    int ci = k & (KCsrc - 1);
    short val = f2h(w[(n * KCsrc + ci) * NSP + j]);   // exact: weights bf16-rounded
    int chunk = k >> 5, lanehi = (k >> 3) & 3, jj = k & 7;
    int nt = n >> 4, lane = lanehi * 16 + (n & 15);
    Bout[((chunk * 4 + nt) * 64 + lane) * 8 + jj] = val;
}

#define RP1 (3456*64)   // 221184
#define RP2 (1728*64)   // 110592
#define RPD (192*64)    // 12288

__global__ void k_prep(const float* w1, const float* w2, const float* w3,
                       const float* wd1, const float* wd2,
                       short* B1, short* B2, short* B3, short* Bd1, short* Bd2,
                       const float* g, const float* b, const float* m, const float* v,
                       float* scale, float* shift){
    int i = blockIdx.x * 256 + threadIdx.x;
    if (i < RP1){ repack_one(w1, B1, i, 128, 7, 27); return; }
    i -= RP1;
    if (i < RP2){ repack_one(w2, B2, i, 64, 6, 27); return; }
    i -= RP2;
    if (i < RP2){ repack_one(w3, B3, i, 64, 6, 27); return; }
    i -= RP2;
    if (i < RPD){ repack_one(wd1, Bd1, i, 64, 6, 3); return; }
    i -= RPD;
    if (i < RPD){ repack_one(wd2, Bd2, i, 64, 6, 3); return; }
    i -= RPD;
    if (i < 5*64){
        float s = g[i] / sqrtf(v[i] + EPS_);
        scale[i] = s;
        shift[i] = b[i] - m[i] * s;
    }
}
#define PREP_TOT (RP1 + 2*RP2 + 2*RPD + 5*64)

// ---------------- voxel count per cell ----------------
__global__ void k_count(const int* coors, int* cntg){
    int v = blockIdx.x * 256 + threadIdx.x;
    if (v >= NV_) return;
    int z = coors[v*4+1], y = coors[v*4+2], x = coors[v*4+3];
    atomicAdd(&cntg[(z*H0_ + y)*W0_ + x], 1);
}

// ---------------- block-aggregated row assignment: ONE atomic per block ----------------
__device__ __forceinline__ int blk_rank(bool act, int* cnt, int& r_out){
    unsigned long long mask = __ballot(act);
    int lane = threadIdx.x & 63, wid = threadIdx.x >> 6;
    int wrank = __popcll(mask & ((1ull << lane) - 1));
    __shared__ int ws[4];
    __shared__ int blkbase;
    if (lane == 0) ws[wid] = __popcll(mask);
    __syncthreads();
    if (threadIdx.x == 0){
        int t0 = ws[0], t1 = ws[1], t2 = ws[2], t3 = ws[3];
        int tot = t0 + t1 + t2 + t3;
        blkbase = tot ? atomicAdd(cnt, tot) : 0;
        ws[0] = 0; ws[1] = t0; ws[2] = t0 + t1; ws[3] = t0 + t1 + t2;
    }
    __syncthreads();
    r_out = blkbase + ws[wid] + wrank;
    return 0;
}

// ---------------- compact level 0 ----------------
__global__ void k_compact0(const int* cntg, int* idx0, int* list0, int* cnt0){
    int c = blockIdx.x * 256 + threadIdx.x;
    bool act = (c < NCELL0) && (cntg[c] > 0);
    int r; blk_rank(act, cnt0, r);
    if (c >= NCELL0) return;
    if (act){
        idx0[c] = r;
        int z = c / HW_; int rem = c - z * HW_;
        int y = rem / W0_; int x = rem - y * W0_;
        list0[r] = (z << 16) | (y << 8) | x;
    } else idx0[c] = -1;
}

// ---------------- compact level 1/2 ----------------
__global__ void k_compact_dn(const int* idxsrc, int* idxdst, int* listdst, int* cnt,
                             int ncell){
    int c = blockIdx.x * 256 + threadIdx.x;
    bool act = false;
    int d = 0, y = 0, x = 0;
    if (c < ncell){
        d = c / HW_; int rem = c - d * HW_;
        y = rem / W0_; x = rem - y * W0_;
        #pragma unroll
        for (int j = 0; j < 3; ++j)
            act = act || (idxsrc[((2*d + j)*H0_ + y)*W0_ + x] >= 0);
    }
    int r; blk_rank(act, cnt, r);
    if (c >= ncell) return;
    if (act){
        idxdst[c] = r;
        listdst[r] = (d << 16) | (y << 8) | x;
    } else idxdst[c] = -1;
}

// ---------------- scatter fp32 features ----------------
__global__ void k_scatter(const float* vf, const int* coors, const int* cntg,
                          const int* idx0, float* feat0f){
    int u = blockIdx.x * 256 + threadIdx.x;
    if (u >= NV_ * 32) return;
    int v = u >> 5, c4 = u & 31;
    int z = coors[v*4+1], y = coors[v*4+2], x = coors[v*4+3];
    int cell = (z*H0_ + y)*W0_ + x;
    int row = idx0[cell];
    float4 s = ((const float4*)(vf + (long)v * 128))[c4];
    float* dst = feat0f + (long)row * 128 + c4 * 4;
    if (cntg[cell] == 1){
        *(float4*)dst = s;
    } else {
        atomicAdd(dst+0, s.x); atomicAdd(dst+1, s.y);
        atomicAdd(dst+2, s.z); atomicAdd(dst+3, s.w);
    }
}

// ---------------- fp32 -> fp16 convert (8 per thread; exact for bf16-rounded values) ----------------
__global__ void k_convert(const float* f, short* b, const int* cntp){
    int n8 = cntp[0] * 16;
    int i = blockIdx.x * 256 + threadIdx.x;
    if (i >= n8) return;
    float4 a = ((const float4*)f)[i*2], c = ((const float4*)f)[i*2+1];
    short o[8] = { f2h(a.x), f2h(a.y), f2h(a.z), f2h(a.w),
                   f2h(c.x), f2h(c.y), f2h(c.z), f2h(c.w) };
    ((int4*)b)[i] = *(int4*)o;
}

// ---------------- fused transposed neighbor tables: nbrT[j*cap + site] ----------------
__global__ void k_nbrs(const int* list0, const int* list1, const int* list2,
                       const int* idx0, const int* idx1,
                       int* nbr0T, int* nbr1T, int* dnb1T, int* dnb2T,
                       const int* counters){
    int job = blockIdx.z;
    int j = blockIdx.y;
    int site = blockIdx.x * 256 + threadIdx.x;
    if (job < 2){
        int M = counters[job];
        if (site >= M) return;
        const int* list = job ? list1 : list0;
        const int* idxg = job ? idx1 : idx0;
        int Dd = job ? D1_ : D0_;
        int cap = job ? CAP1 : CAP0;
        int cell = list[site];
        int z = cell >> 16, y = (cell >> 8) & 255, x = cell & 255;
        int nz = z + j/9 - 1, ny = y + (j/3)%3 - 1, nx = x + j%3 - 1;
        int r = -1;
        if ((unsigned)nz < (unsigned)Dd && (unsigned)ny < H0_ && (unsigned)nx < W0_)
            r = idxg[(nz*H0_ + ny)*W0_ + nx];
        (job ? nbr1T : nbr0T)[j * cap + site] = r;
    } else {
        if (j >= 3) return;
        int lvl = job - 2;
        int M = counters[lvl + 1];
        if (site >= M) return;
        const int* list = lvl ? list2 : list1;
        const int* idxg = lvl ? idx1 : idx0;
        int cap = lvl ? CAP2 : CAP1;
        int cell = list[site];
        int d = cell >> 16, y = (cell >> 8) & 255, x = cell & 255;
        (lvl ? dnb2T : dnb1T)[j * cap + site] = idxg[((2*d + j)*H0_ + y)*W0_ + x];
    }
}

// ---------------- gather-GEMM: wave-split-K, ZERO barriers in the K-loop ----------------
// Block = one 16-row M-tile. Flatten (tap,kc) -> chunks c in [0, NNBR*NCH);
// wave w handles c = w, w+4, ... (kc is wave-constant for NCH in {2,4}).
// Each chunk: 1 nbr read + 1 A-slice + 4 B-frags + 4 MFMAs, double-buffered,
// no __syncthreads -> loads pipeline freely across chunks (fine-grained vmcnt).
// End: partial 16x64 C per wave -> LDS (pad 68: 2-way, free) -> sum -> BN+ReLU.
template<int NNBR, int NCH, bool FINAL>
__global__ __launch_bounds__(256) void k_gemm(
    const short* __restrict__ featA, const int* __restrict__ nbrT, int nstride,
    const short* __restrict__ Bs, short* __restrict__ out,
    const int* __restrict__ cntp,
    const float* __restrict__ scale, const float* __restrict__ shift,
    const int* __restrict__ list, float* __restrict__ dout)
{
    __shared__ float Cred[4][16][68];        // 17.4 KB, padded: quad stride 16 mod 32
    const int NCHUNK = NNBR * NCH;
    const int ROWS = NCH * 32;               // shorts per A row
    int M = *cntp;
    int m0 = blockIdx.x * 16;
    if (m0 >= M) return;
    int tid = threadIdx.x;
    int wave = tid >> 6, lane = tid & 63;
    int m16 = lane & 15;
    int q = lane >> 4;
    int row = m0 + m16;
    bool ok = row < M;

    floatx4 acc[4] = {};
    const f16x8 z8 = {0,0,0,0,0,0,0,0};
    const short* Bl = Bs + (long)lane * 8;

    f16x8 Ab[2];
    f16x8 Bb[2][4];
    bool any[2];

    auto loadChunk = [&](int c, int buf){
        int t = c / NCH, kc = c - t * NCH;
        int r = ok ? nbrT[t * nstride + row] : -1;
        any[buf] = (__ballot(r >= 0) != 0);
        Ab[buf] = (r >= 0) ? *(const f16x8*)(featA + (long)r*ROWS + kc*32 + q*8) : z8;
        const short* bp = Bl + (long)c * 4 * 512;
        #pragma unroll
        for (int nt = 0; nt < 4; ++nt)
            Bb[buf][nt] = *(const f16x8*)(bp + nt * 512);
    };

    if (wave < NCHUNK) loadChunk(wave, 0);
    #pragma unroll
    for (int i = 0; ; ++i){
        int c = wave + i * 4;
        if (c >= NCHUNK) break;
        if (c + 4 < NCHUNK) loadChunk(c + 4, (i + 1) & 1);
        if (any[i & 1]){
            f16x8 a = Ab[i & 1];
            #pragma unroll
            for (int nt = 0; nt < 4; ++nt)
                acc[nt] = __builtin_amdgcn_mfma_f32_16x16x32_f16(a, Bb[i & 1][nt], acc[nt], 0, 0, 0);
        }
    }

    // write partials: acc[nt][r] = C[row=q*4+r][col=nt*16+m16]
    #pragma unroll
    for (int nt = 0; nt < 4; ++nt)
        #pragma unroll
        for (int r = 0; r < 4; ++r)
            Cred[wave][q*4 + r][nt*16 + m16] = acc[nt][r];
    __syncthreads();

    // cooperative reduce + BN/ReLU + store: 1024 values, 4 per thread
    #pragma unroll
    for (int v = tid; v < 1024; v += 256){
        int rw = v >> 6, col = v & 63;
        int site = m0 + rw;
        if (site < M){
            float s = Cred[0][rw][col] + Cred[1][rw][col]
                    + Cred[2][rw][col] + Cred[3][rw][col];
            float y = fmaxf(s * scale[col] + shift[col], 0.f);
            if (FINAL){
                int cell = list[site];
                int d = cell >> 16, yy = (cell >> 8) & 255, xx = cell & 255;
                dout[((col*4 + d)*H0_ + yy)*W0_ + xx] = y;
            } else {
                out[(long)site*64 + col] = f2h(y);
            }
        }
    }
}

extern "C" void kernel_launch(void* const* d_in, const int* in_sizes, int n_in,
                              void* d_out, int out_size, void* d_ws, size_t ws_size,
                              hipStream_t stream){
    const float* vf   = (const float*)d_in[0];
    const int*   coors= (const int*)  d_in[1];
    const float* w1   = (const float*)d_in[3];
    const float* wd1  = (const float*)d_in[4];
    const float* w2   = (const float*)d_in[5];
    const float* w3   = (const float*)d_in[6];
    const float* wd2  = (const float*)d_in[7];
    const float* bng  = (const float*)d_in[8];
    const float* bnb  = (const float*)d_in[9];
    const float* bnm  = (const float*)d_in[10];
    const float* bnv  = (const float*)d_in[11];
    float* dout = (float*)d_out;

    char* ws = (char*)d_ws;
    size_t off = 0;
    auto alloc = [&](size_t bytes)->char* {
        char* p = ws + off;
        off += (bytes + 255) & ~(size_t)255;
        return p;
    };

    int*   counters = (int*)  alloc(256);                    // [0]=cnt0 [1]=cnt1 [2]=cnt2
    int*   cntg     = (int*)  alloc((size_t)NCELL0 * 4);
    int*   idx0     = (int*)  alloc((size_t)NCELL0 * 4);
    int*   idx1     = (int*)  alloc((size_t)NCELL1 * 4);
    int*   idx2     = (int*)  alloc((size_t)NCELL2 * 4);
    int*   list0    = (int*)  alloc((size_t)CAP0 * 4);
    int*   list1    = (int*)  alloc((size_t)CAP1 * 4);
    int*   list2    = (int*)  alloc((size_t)CAP2 * 4);
    float* feat0f   = (float*)alloc((size_t)CAP0 * 128 * 4);
    short* feat0h   = (short*)alloc((size_t)CAP0 * 128 * 2);  // L1 input, 128ch fp16
    short* feat1    = (short*)alloc((size_t)CAP0 * 64 * 2);   // 64ch fp16 activations
    short* featd1   = (short*)alloc((size_t)CAP1 * 64 * 2);
    short* feat2    = (short*)alloc((size_t)CAP1 * 64 * 2);
    short* feat3    = (short*)alloc((size_t)CAP1 * 64 * 2);
    int*   nbr0T    = (int*)  alloc((size_t)CAP0 * 27 * 4);
    int*   nbr1T    = (int*)  alloc((size_t)CAP1 * 27 * 4);
    int*   dnb1T    = (int*)  alloc((size_t)CAP1 * 3 * 4);
    int*   dnb2T    = (int*)  alloc((size_t)CAP2 * 3 * 4);
    short* B1  = (short*)alloc((size_t)3456 * 64 * 2);
    short* B2  = (short*)alloc((size_t)1728 * 64 * 2);
    short* B3  = (short*)alloc((size_t)1728 * 64 * 2);
    short* Bd1 = (short*)alloc((size_t)192 * 64 * 2);
    short* Bd2 = (short*)alloc((size_t)192 * 64 * 2);
    float* bnscale = (float*)alloc(5 * 64 * 4);
    float* bnshift = (float*)alloc(5 * 64 * 4);

    // ---- zero (ws/d_out poisoned 0xAA) ----
    hipMemsetAsync(counters, 0, 256 + (size_t)NCELL0 * 4, stream);
    hipMemsetAsync(feat0f, 0, (size_t)CAP0 * 128 * 4, stream);
    hipMemsetAsync(dout, 0, (size_t)out_size * 4, stream);

    // ---- constants ----
    k_prep<<<(PREP_TOT + 255)/256, 256, 0, stream>>>(w1, w2, w3, wd1, wd2,
        B1, B2, B3, Bd1, Bd2, bng, bnb, bnm, bnv, bnscale, bnshift);

    // ---- sparse structure ----
    k_count<<<(NV_ + 255)/256, 256, 0, stream>>>(coors, cntg);
    k_compact0<<<(NCELL0 + 255)/256, 256, 0, stream>>>(cntg, idx0, list0, counters + 0);
    k_scatter<<<(NV_*32 + 255)/256, 256, 0, stream>>>(vf, coors, cntg, idx0, feat0f);
    k_convert<<<(CAP0*16 + 255)/256, 256, 0, stream>>>(feat0f, feat0h, counters + 0);
    k_compact_dn<<<(NCELL1 + 255)/256, 256, 0, stream>>>(idx0, idx1, list1, counters + 1, NCELL1);
    k_compact_dn<<<(NCELL2 + 255)/256, 256, 0, stream>>>(idx1, idx2, list2, counters + 2, NCELL2);

    dim3 gn((CAP2 + 255)/256, 27, 4);
    k_nbrs<<<gn, 256, 0, stream>>>(list0, list1, list2, idx0, idx1,
                                   nbr0T, nbr1T, dnb1T, dnb2T, counters);

    // ---- the five gather-GEMMs (fp16, M-tile 16, wave-split-K, no barriers) ----
    k_gemm<27,4,false><<<(CAP0+15)/16, 256, 0, stream>>>(feat0h, nbr0T, CAP0, B1, feat1,
        counters + 0, bnscale + 0,   bnshift + 0,   nullptr, nullptr);
    k_gemm<3,2,false><<<(CAP1+15)/16, 256, 0, stream>>>(feat1, dnb1T, CAP1, Bd1, featd1,
        counters + 1, bnscale + 64,  bnshift + 64,  nullptr, nullptr);
    k_gemm<27,2,false><<<(CAP1+15)/16, 256, 0, stream>>>(featd1, nbr1T, CAP1, B2, feat2,
        counters + 1, bnscale + 128, bnshift + 128, nullptr, nullptr);
    k_gemm<27,2,false><<<(CAP1+15)/16, 256, 0, stream>>>(feat2, nbr1T, CAP1, B3, feat3,
        counters + 1, bnscale + 192, bnshift + 192, nullptr, nullptr);
    k_gemm<3,2,true><<<(CAP2+15)/16, 256, 0, stream>>>(feat3, dnb2T, CAP2, Bd2, nullptr,
        counters + 2, bnscale + 256, bnshift + 256, list2, dout);
}

// Round 14
// 351.933 us; speedup vs baseline: 22.8465x; 22.8465x over previous
//
#include <hip/hip_runtime.h>

typedef float floatx4 __attribute__((ext_vector_type(4)));
typedef _Float16 f16x8 __attribute__((ext_vector_type(8)));

#define D0_ 19
#define H0_ 200
#define W0_ 176
#define HW_ (H0_*W0_)          // 35200
#define NCELL0 (D0_*HW_)       // 668800
#define D1_ 9
#define NCELL1 (D1_*HW_)       // 316800
#define D2_ 4
#define NCELL2 (D2_*HW_)       // 140800
#define NV_ 40000
#define CAP0 40000
#define CAP1 80000
#define CAP2 140800
#define EPS_ 1e-3f

__device__ __forceinline__ short f2h(float f){
    _Float16 h = (_Float16)f;
    short s; __builtin_memcpy(&s, &h, 2); return s;
}

// ---------------- fused constant prep: BN consts + 5 weight repacks (fp16) ----------------
__device__ __forceinline__ void repack_one(const float* w, short* Bout, int i,
                                           int KCsrc, int kshift, int NSP){
    int k = i >> 6, n = i & 63;
    int j = k >> kshift;
    int ci = k & (KCsrc - 1);
    short val = f2h(w[(n * KCsrc + ci) * NSP + j]);   // exact: weights bf16-rounded
    int chunk = k >> 5, lanehi = (k >> 3) & 3, jj = k & 7;
    int nt = n >> 4, lane = lanehi * 16 + (n & 15);
    Bout[((chunk * 4 + nt) * 64 + lane) * 8 + jj] = val;
}

#define RP1 (3456*64)   // 221184
#define RP2 (1728*64)   // 110592
#define RPD (192*64)    // 12288

__global__ void k_prep(const float* w1, const float* w2, const float* w3,
                       const float* wd1, const float* wd2,
                       short* B1, short* B2, short* B3, short* Bd1, short* Bd2,
                       const float* g, const float* b, const float* m, const float* v,
                       float* scale, float* shift){
    int i = blockIdx.x * 256 + threadIdx.x;
    if (i < RP1){ repack_one(w1, B1, i, 128, 7, 27); return; }
    i -= RP1;
    if (i < RP2){ repack_one(w2, B2, i, 64, 6, 27); return; }
    i -= RP2;
    if (i < RP2){ repack_one(w3, B3, i, 64, 6, 27); return; }
    i -= RP2;
    if (i < RPD){ repack_one(wd1, Bd1, i, 64, 6, 3); return; }
    i -= RPD;
    if (i < RPD){ repack_one(wd2, Bd2, i, 64, 6, 3); return; }
    i -= RPD;
    if (i < 5*64){
        float s = g[i] / sqrtf(v[i] + EPS_);
        scale[i] = s;
        shift[i] = b[i] - m[i] * s;
    }
}
#define PREP_TOT (RP1 + 2*RP2 + 2*RPD + 5*64)

// ---------------- voxel count per cell ----------------
__global__ void k_count(const int* coors, int* cntg){
    int v = blockIdx.x * 256 + threadIdx.x;
    if (v >= NV_) return;
    int z = coors[v*4+1], y = coors[v*4+2], x = coors[v*4+3];
    atomicAdd(&cntg[(z*H0_ + y)*W0_ + x], 1);
}

// ---------------- block-aggregated row assignment: ONE atomic per block ----------------
__device__ __forceinline__ int blk_rank(bool act, int* cnt, int& r_out){
    unsigned long long mask = __ballot(act);
    int lane = threadIdx.x & 63, wid = threadIdx.x >> 6;
    int wrank = __popcll(mask & ((1ull << lane) - 1));
    __shared__ int ws[4];
    __shared__ int blkbase;
    if (lane == 0) ws[wid] = __popcll(mask);
    __syncthreads();
    if (threadIdx.x == 0){
        int t0 = ws[0], t1 = ws[1], t2 = ws[2], t3 = ws[3];
        int tot = t0 + t1 + t2 + t3;
        blkbase = tot ? atomicAdd(cnt, tot) : 0;
        ws[0] = 0; ws[1] = t0; ws[2] = t0 + t1; ws[3] = t0 + t1 + t2;
    }
    __syncthreads();
    r_out = blkbase + ws[wid] + wrank;
    return 0;
}

// ---------------- compact level 0 ----------------
__global__ void k_compact0(const int* cntg, int* idx0, int* list0, int* cnt0){
    int c = blockIdx.x * 256 + threadIdx.x;
    bool act = (c < NCELL0) && (cntg[c] > 0);
    int r; blk_rank(act, cnt0, r);
    if (c >= NCELL0) return;
    if (act){
        idx0[c] = r;
        int z = c / HW_; int rem = c - z * HW_;
        int y = rem / W0_; int x = rem - y * W0_;
        list0[r] = (z << 16) | (y << 8) | x;
    } else idx0[c] = -1;
}

// ---------------- compact level 1/2 ----------------
__global__ void k_compact_dn(const int* idxsrc, int* idxdst, int* listdst, int* cnt,
                             int ncell){
    int c = blockIdx.x * 256 + threadIdx.x;
    bool act = false;
    int d = 0, y = 0, x = 0;
    if (c < ncell){
        d = c / HW_; int rem = c - d * HW_;
        y = rem / W0_; x = rem - y * W0_;
        #pragma unroll
        for (int j = 0; j < 3; ++j)
            act = act || (idxsrc[((2*d + j)*H0_ + y)*W0_ + x] >= 0);
    }
    int r; blk_rank(act, cnt, r);
    if (c >= ncell) return;
    if (act){
        idxdst[c] = r;
        listdst[r] = (d << 16) | (y << 8) | x;
    } else idxdst[c] = -1;
}

// ---------------- scatter fp32 features ----------------
__global__ void k_scatter(const float* vf, const int* coors, const int* cntg,
                          const int* idx0, float* feat0f){
    int u = blockIdx.x * 256 + threadIdx.x;
    if (u >= NV_ * 32) return;
    int v = u >> 5, c4 = u & 31;
    int z = coors[v*4+1], y = coors[v*4+2], x = coors[v*4+3];
    int cell = (z*H0_ + y)*W0_ + x;
    int row = idx0[cell];
    float4 s = ((const float4*)(vf + (long)v * 128))[c4];
    float* dst = feat0f + (long)row * 128 + c4 * 4;
    if (cntg[cell] == 1){
        *(float4*)dst = s;
    } else {
        atomicAdd(dst+0, s.x); atomicAdd(dst+1, s.y);
        atomicAdd(dst+2, s.z); atomicAdd(dst+3, s.w);
    }
}

// ---------------- fp32 -> fp16 convert (8 per thread; exact for bf16-rounded values) ----------------
__global__ void k_convert(const float* f, short* b, const int* cntp){
    int n8 = cntp[0] * 16;
    int i = blockIdx.x * 256 + threadIdx.x;
    if (i >= n8) return;
    float4 a = ((const float4*)f)[i*2], c = ((const float4*)f)[i*2+1];
    short o[8] = { f2h(a.x), f2h(a.y), f2h(a.z), f2h(a.w),
                   f2h(c.x), f2h(c.y), f2h(c.z), f2h(c.w) };
    ((int4*)b)[i] = *(int4*)o;
}

// ---------------- fused transposed neighbor tables: nbrT[j*cap + site] ----------------
__global__ void k_nbrs(const int* list0, const int* list1, const int* list2,
                       const int* idx0, const int* idx1,
                       int* nbr0T, int* nbr1T, int* dnb1T, int* dnb2T,
                       const int* counters){
    int job = blockIdx.z;
    int j = blockIdx.y;
    int site = blockIdx.x * 256 + threadIdx.x;
    if (job < 2){
        int M = counters[job];
        if (site >= M) return;
        const int* list = job ? list1 : list0;
        const int* idxg = job ? idx1 : idx0;
        int Dd = job ? D1_ : D0_;
        int cap = job ? CAP1 : CAP0;
        int cell = list[site];
        int z = cell >> 16, y = (cell >> 8) & 255, x = cell & 255;
        int nz = z + j/9 - 1, ny = y + (j/3)%3 - 1, nx = x + j%3 - 1;
        int r = -1;
        if ((unsigned)nz < (unsigned)Dd && (unsigned)ny < H0_ && (unsigned)nx < W0_)
            r = idxg[(nz*H0_ + ny)*W0_ + nx];
        (job ? nbr1T : nbr0T)[j * cap + site] = r;
    } else {
        if (j >= 3) return;
        int lvl = job - 2;
        int M = counters[lvl + 1];
        if (site >= M) return;
        const int* list = lvl ? list2 : list1;
        const int* idxg = lvl ? idx1 : idx0;
        int cap = lvl ? CAP2 : CAP1;
        int cell = list[site];
        int d = cell >> 16, y = (cell >> 8) & 255, x = cell & 255;
        (lvl ? dnb2T : dnb1T)[j * cap + site] = idxg[((2*d + j)*H0_ + y)*W0_ + x];
    }
}

// ---------------- gather-GEMM: wave-split-K, zero barriers, FULLY UNROLLED ----------------
// Block = 32-row M-tile (2 row-groups of 16, both owned by every wave).
// Chunks c in [0,NNBR*NCH) split round-robin across 4 waves; NITER constexpr ->
// full unroll -> all double-buffer indices static (registers, no scratch).
// Per chunk: 2 nbr + 2 A-slices + 4 B-frags + 8 MFMAs, no __syncthreads.
// End: partial C per wave -> padded LDS (2-way, free) -> sum -> BN+ReLU.
template<int NNBR, int NCH, bool FINAL>
__global__ __launch_bounds__(256) void k_gemm(
    const short* __restrict__ featA, const int* __restrict__ nbrT, int nstride,
    const short* __restrict__ Bs, short* __restrict__ out,
    const int* __restrict__ cntp,
    const float* __restrict__ scale, const float* __restrict__ shift,
    const int* __restrict__ list, float* __restrict__ dout)
{
    __shared__ float Cred[4][32][68];        // 34.8 KB
    constexpr int NCHUNK = NNBR * NCH;
    constexpr int NITER = (NCHUNK + 3) / 4;
    const int ROWS = NCH * 32;               // shorts per A row
    int M = *cntp;
    int m0 = blockIdx.x * 32;
    if (m0 >= M) return;
    int tid = threadIdx.x;
    int wave = tid >> 6, lane = tid & 63;
    int m16 = lane & 15;
    int q = lane >> 4;
    int row0 = m0 + m16;                     // group 0
    int row1 = m0 + 16 + m16;                // group 1
    bool ok0 = row0 < M, ok1 = row1 < M;

    floatx4 acc0[4] = {}, acc1[4] = {};
    const f16x8 z8 = {0,0,0,0,0,0,0,0};
    const short* Bl = Bs + (long)lane * 8;

    f16x8 Ab0[2], Ab1[2];
    f16x8 Bb[2][4];
    bool any0[2], any1[2];

    auto loadChunk = [&](int c, int buf){
        int t = c / NCH, kc = c & (NCH - 1);
        int r0 = ok0 ? nbrT[t * nstride + row0] : -1;
        int r1 = ok1 ? nbrT[t * nstride + row1] : -1;
        any0[buf] = (__ballot(r0 >= 0) != 0);
        any1[buf] = (__ballot(r1 >= 0) != 0);
        Ab0[buf] = (r0 >= 0) ? *(const f16x8*)(featA + (long)r0*ROWS + kc*32 + q*8) : z8;
        Ab1[buf] = (r1 >= 0) ? *(const f16x8*)(featA + (long)r1*ROWS + kc*32 + q*8) : z8;
        const short* bp = Bl + (long)c * 4 * 512;
        #pragma unroll
        for (int nt = 0; nt < 4; ++nt)
            Bb[buf][nt] = *(const f16x8*)(bp + nt * 512);
    };

    if (wave < NCHUNK) loadChunk(wave, 0);
    #pragma unroll
    for (int i = 0; i < NITER; ++i){
        int c = wave + i * 4;
        bool valid = (c < NCHUNK);
        int cn = c + 4;
        if (cn < NCHUNK) loadChunk(cn, (i + 1) & 1);
        if (valid){
            if (any0[i & 1]){
                f16x8 a = Ab0[i & 1];
                #pragma unroll
                for (int nt = 0; nt < 4; ++nt)
                    acc0[nt] = __builtin_amdgcn_mfma_f32_16x16x32_f16(a, Bb[i & 1][nt], acc0[nt], 0, 0, 0);
            }
            if (any1[i & 1]){
                f16x8 a = Ab1[i & 1];
                #pragma unroll
                for (int nt = 0; nt < 4; ++nt)
                    acc1[nt] = __builtin_amdgcn_mfma_f32_16x16x32_f16(a, Bb[i & 1][nt], acc1[nt], 0, 0, 0);
            }
        }
    }

    // write partials: acc[nt][r] = C[row=q*4+r][col=nt*16+m16]
    #pragma unroll
    for (int nt = 0; nt < 4; ++nt)
        #pragma unroll
        for (int r = 0; r < 4; ++r){
            Cred[wave][q*4 + r][nt*16 + m16]      = acc0[nt][r];
            Cred[wave][16 + q*4 + r][nt*16 + m16] = acc1[nt][r];
        }
    __syncthreads();

    // cooperative reduce + BN/ReLU + store: 2048 values, 8 per thread
    #pragma unroll
    for (int v = tid; v < 2048; v += 256){
        int rw = v >> 6, col = v & 63;
        int site = m0 + rw;
        if (site < M){
            float s = Cred[0][rw][col] + Cred[1][rw][col]
                    + Cred[2][rw][col] + Cred[3][rw][col];
            float y = fmaxf(s * scale[col] + shift[col], 0.f);
            if (FINAL){
                int cell = list[site];
                int d = cell >> 16, yy = (cell >> 8) & 255, xx = cell & 255;
                dout[((col*4 + d)*H0_ + yy)*W0_ + xx] = y;
            } else {
                out[(long)site*64 + col] = f2h(y);
            }
        }
    }
}

extern "C" void kernel_launch(void* const* d_in, const int* in_sizes, int n_in,
                              void* d_out, int out_size, void* d_ws, size_t ws_size,
                              hipStream_t stream){
    const float* vf   = (const float*)d_in[0];
    const int*   coors= (const int*)  d_in[1];
    const float* w1   = (const float*)d_in[3];
    const float* wd1  = (const float*)d_in[4];
    const float* w2   = (const float*)d_in[5];
    const float* w3   = (const float*)d_in[6];
    const float* wd2  = (const float*)d_in[7];
    const float* bng  = (const float*)d_in[8];
    const float* bnb  = (const float*)d_in[9];
    const float* bnm  = (const float*)d_in[10];
    const float* bnv  = (const float*)d_in[11];
    float* dout = (float*)d_out;

    char* ws = (char*)d_ws;
    size_t off = 0;
    auto alloc = [&](size_t bytes)->char* {
        char* p = ws + off;
        off += (bytes + 255) & ~(size_t)255;
        return p;
    };

    int*   counters = (int*)  alloc(256);                    // [0]=cnt0 [1]=cnt1 [2]=cnt2
    int*   cntg     = (int*)  alloc((size_t)NCELL0 * 4);
    int*   idx0     = (int*)  alloc((size_t)NCELL0 * 4);
    int*   idx1     = (int*)  alloc((size_t)NCELL1 * 4);
    int*   idx2     = (int*)  alloc((size_t)NCELL2 * 4);
    int*   list0    = (int*)  alloc((size_t)CAP0 * 4);
    int*   list1    = (int*)  alloc((size_t)CAP1 * 4);
    int*   list2    = (int*)  alloc((size_t)CAP2 * 4);
    float* feat0f   = (float*)alloc((size_t)CAP0 * 128 * 4);
    short* feat0h   = (short*)alloc((size_t)CAP0 * 128 * 2);  // L1 input, 128ch fp16
    short* feat1    = (short*)alloc((size_t)CAP0 * 64 * 2);   // 64ch fp16 activations
    short* featd1   = (short*)alloc((size_t)CAP1 * 64 * 2);
    short* feat2    = (short*)alloc((size_t)CAP1 * 64 * 2);
    short* feat3    = (short*)alloc((size_t)CAP1 * 64 * 2);
    int*   nbr0T    = (int*)  alloc((size_t)CAP0 * 27 * 4);
    int*   nbr1T    = (int*)  alloc((size_t)CAP1 * 27 * 4);
    int*   dnb1T    = (int*)  alloc((size_t)CAP1 * 3 * 4);
    int*   dnb2T    = (int*)  alloc((size_t)CAP2 * 3 * 4);
    short* B1  = (short*)alloc((size_t)3456 * 64 * 2);
    short* B2  = (short*)alloc((size_t)1728 * 64 * 2);
    short* B3  = (short*)alloc((size_t)1728 * 64 * 2);
    short* Bd1 = (short*)alloc((size_t)192 * 64 * 2);
    short* Bd2 = (short*)alloc((size_t)192 * 64 * 2);
    float* bnscale = (float*)alloc(5 * 64 * 4);
    float* bnshift = (float*)alloc(5 * 64 * 4);

    // ---- zero (ws/d_out poisoned 0xAA) ----
    hipMemsetAsync(counters, 0, 256 + (size_t)NCELL0 * 4, stream);
    hipMemsetAsync(feat0f, 0, (size_t)CAP0 * 128 * 4, stream);
    hipMemsetAsync(dout, 0, (size_t)out_size * 4, stream);

    // ---- constants ----
    k_prep<<<(PREP_TOT + 255)/256, 256, 0, stream>>>(w1, w2, w3, wd1, wd2,
        B1, B2, B3, Bd1, Bd2, bng, bnb, bnm, bnv, bnscale, bnshift);

    // ---- sparse structure ----
    k_count<<<(NV_ + 255)/256, 256, 0, stream>>>(coors, cntg);
    k_compact0<<<(NCELL0 + 255)/256, 256, 0, stream>>>(cntg, idx0, list0, counters + 0);
    k_scatter<<<(NV_*32 + 255)/256, 256, 0, stream>>>(vf, coors, cntg, idx0, feat0f);
    k_convert<<<(CAP0*16 + 255)/256, 256, 0, stream>>>(feat0f, feat0h, counters + 0);
    k_compact_dn<<<(NCELL1 + 255)/256, 256, 0, stream>>>(idx0, idx1, list1, counters + 1, NCELL1);
    k_compact_dn<<<(NCELL2 + 255)/256, 256, 0, stream>>>(idx1, idx2, list2, counters + 2, NCELL2);

    dim3 gn((CAP2 + 255)/256, 27, 4);
    k_nbrs<<<gn, 256, 0, stream>>>(list0, list1, list2, idx0, idx1,
                                   nbr0T, nbr1T, dnb1T, dnb2T, counters);

    // ---- the five gather-GEMMs (fp16, M-tile 32, wave-split-K, no K-loop barriers) ----
    k_gemm<27,4,false><<<(CAP0+31)/32, 256, 0, stream>>>(feat0h, nbr0T, CAP0, B1, feat1,
        counters + 0, bnscale + 0,   bnshift + 0,   nullptr, nullptr);
    k_gemm<3,2,false><<<(CAP1+31)/32, 256, 0, stream>>>(feat1, dnb1T, CAP1, Bd1, featd1,
        counters + 1, bnscale + 64,  bnshift + 64,  nullptr, nullptr);
    k_gemm<27,2,false><<<(CAP1+31)/32, 256, 0, stream>>>(featd1, nbr1T, CAP1, B2, feat2,
        counters + 1, bnscale + 128, bnshift + 128, nullptr, nullptr);
    k_gemm<27,2,false><<<(CAP1+31)/32, 256, 0, stream>>>(feat2, nbr1T, CAP1, B3, feat3,
        counters + 1, bnscale + 192, bnshift + 192, nullptr, nullptr);
    k_gemm<3,2,true><<<(CAP2+31)/32, 256, 0, stream>>>(feat3, dnb2T, CAP2, Bd2, nullptr,
        counters + 2, bnscale + 256, bnshift + 256, list2, dout);
}

// Round 15
// 288.881 us; speedup vs baseline: 27.8331x; 1.2183x over previous
//
#include <hip/hip_runtime.h>

typedef float floatx4 __attribute__((ext_vector_type(4)));
typedef _Float16 f16x8 __attribute__((ext_vector_type(8)));

#define D0_ 19
#define H0_ 200
#define W0_ 176
#define HW_ (H0_*W0_)          // 35200
#define NCELL0 (D0_*HW_)       // 668800
#define D1_ 9
#define NCELL1 (D1_*HW_)       // 316800
#define D2_ 4
#define NCELL2 (D2_*HW_)       // 140800
#define NV_ 40000
#define CAP0 40000
#define CAP1 80000
#define CAP2 140800
#define EPS_ 1e-3f

typedef __attribute__((address_space(1))) const unsigned int* gas_t;
typedef __attribute__((address_space(3))) unsigned int* las_t;

__device__ __forceinline__ short f2h(float f){
    _Float16 h = (_Float16)f;
    short s; __builtin_memcpy(&s, &h, 2); return s;
}

// ---------------- fused constant prep: BN consts + 5 weight repacks + voxel count ----------------
__device__ __forceinline__ void repack_one(const float* w, short* Bout, int i,
                                           int KCsrc, int kshift, int NSP){
    int k = i >> 6, n = i & 63;
    int j = k >> kshift;
    int ci = k & (KCsrc - 1);
    short val = f2h(w[(n * KCsrc + ci) * NSP + j]);   // exact: weights bf16-rounded
    int chunk = k >> 5, lanehi = (k >> 3) & 3, jj = k & 7;
    int nt = n >> 4, lane = lanehi * 16 + (n & 15);
    Bout[((chunk * 4 + nt) * 64 + lane) * 8 + jj] = val;
}

#define RP1 (3456*64)   // 221184
#define RP2 (1728*64)   // 110592
#define RPD (192*64)    // 12288

__global__ void k_prep(const float* w1, const float* w2, const float* w3,
                       const float* wd1, const float* wd2,
                       short* B1, short* B2, short* B3, short* Bd1, short* Bd2,
                       const float* g, const float* b, const float* m, const float* v,
                       float* scale, float* shift,
                       const int* coors, int* cntg){
    int i = blockIdx.x * 256 + threadIdx.x;
    if (i < RP1){ repack_one(w1, B1, i, 128, 7, 27); return; }
    i -= RP1;
    if (i < RP2){ repack_one(w2, B2, i, 64, 6, 27); return; }
    i -= RP2;
    if (i < RP2){ repack_one(w3, B3, i, 64, 6, 27); return; }
    i -= RP2;
    if (i < RPD){ repack_one(wd1, Bd1, i, 64, 6, 3); return; }
    i -= RPD;
    if (i < RPD){ repack_one(wd2, Bd2, i, 64, 6, 3); return; }
    i -= RPD;
    if (i < 5*64){
        float s = g[i] / sqrtf(v[i] + EPS_);
        scale[i] = s;
        shift[i] = b[i] - m[i] * s;
        return;
    }
    i -= 5*64;
    if (i < NV_){
        int z = coors[i*4+1], y = coors[i*4+2], x = coors[i*4+3];
        atomicAdd(&cntg[(z*H0_ + y)*W0_ + x], 1);
    }
}
#define PREP_TOT (RP1 + 2*RP2 + 2*RPD + 5*64 + NV_)

// ---------------- block-aggregated row assignment: ONE atomic per block ----------------
__device__ __forceinline__ int blk_rank(bool act, int* cnt, int& r_out){
    unsigned long long mask = __ballot(act);
    int lane = threadIdx.x & 63, wid = threadIdx.x >> 6;
    int wrank = __popcll(mask & ((1ull << lane) - 1));
    __shared__ int ws[4];
    __shared__ int blkbase;
    if (lane == 0) ws[wid] = __popcll(mask);
    __syncthreads();
    if (threadIdx.x == 0){
        int t0 = ws[0], t1 = ws[1], t2 = ws[2], t3 = ws[3];
        int tot = t0 + t1 + t2 + t3;
        blkbase = tot ? atomicAdd(cnt, tot) : 0;
        ws[0] = 0; ws[1] = t0; ws[2] = t0 + t1; ws[3] = t0 + t1 + t2;
    }
    __syncthreads();
    r_out = blkbase + ws[wid] + wrank;
    return 0;
}

// ---------------- compact level 0 ----------------
__global__ void k_compact0(const int* cntg, int* idx0, int* list0, int* cnt0){
    int c = blockIdx.x * 256 + threadIdx.x;
    bool act = (c < NCELL0) && (cntg[c] > 0);
    int r; blk_rank(act, cnt0, r);
    if (c >= NCELL0) return;
    if (act){
        idx0[c] = r;
        int z = c / HW_; int rem = c - z * HW_;
        int y = rem / W0_; int x = rem - y * W0_;
        list0[r] = (z << 16) | (y << 8) | x;
    } else idx0[c] = -1;
}

// ---------------- compact level 1/2 ----------------
__global__ void k_compact_dn(const int* idxsrc, int* idxdst, int* listdst, int* cnt,
                             int ncell){
    int c = blockIdx.x * 256 + threadIdx.x;
    bool act = false;
    int d = 0, y = 0, x = 0;
    if (c < ncell){
        d = c / HW_; int rem = c - d * HW_;
        y = rem / W0_; x = rem - y * W0_;
        #pragma unroll
        for (int j = 0; j < 3; ++j)
            act = act || (idxsrc[((2*d + j)*H0_ + y)*W0_ + x] >= 0);
    }
    int r; blk_rank(act, cnt, r);
    if (c >= ncell) return;
    if (act){
        idxdst[c] = r;
        listdst[r] = (d << 16) | (y << 8) | x;
    } else idxdst[c] = -1;
}

// ---------------- scatter fp32 features ----------------
__global__ void k_scatter(const float* vf, const int* coors, const int* cntg,
                          const int* idx0, float* feat0f){
    int u = blockIdx.x * 256 + threadIdx.x;
    if (u >= NV_ * 32) return;
    int v = u >> 5, c4 = u & 31;
    int z = coors[v*4+1], y = coors[v*4+2], x = coors[v*4+3];
    int cell = (z*H0_ + y)*W0_ + x;
    int row = idx0[cell];
    float4 s = ((const float4*)(vf + (long)v * 128))[c4];
    float* dst = feat0f + (long)row * 128 + c4 * 4;
    if (cntg[cell] == 1){
        *(float4*)dst = s;
    } else {
        atomicAdd(dst+0, s.x); atomicAdd(dst+1, s.y);
        atomicAdd(dst+2, s.z); atomicAdd(dst+3, s.w);
    }
}

// ---------------- fp32 -> fp16 convert ----------------
__global__ void k_convert(const float* f, short* b, const int* cntp){
    int n8 = cntp[0] * 16;
    int i = blockIdx.x * 256 + threadIdx.x;
    if (i >= n8) return;
    float4 a = ((const float4*)f)[i*2], c = ((const float4*)f)[i*2+1];
    short o[8] = { f2h(a.x), f2h(a.y), f2h(a.z), f2h(a.w),
                   f2h(c.x), f2h(c.y), f2h(c.z), f2h(c.w) };
    ((int4*)b)[i] = *(int4*)o;
}

// ---------------- 27-tap gather-GEMM: inline neighbor calc, M-tile 64, LDS-staged B ----------------
// Neighbor rows computed from list (packed cell/row, 1 load) + idx grid (small, L2-hot)
// instead of the 13MB nbrT table -> one less L3 hop in the per-tap chain.
// A prefetch depth 2 (3 rotating register buffers, indices compile-time);
// B(t+1) async-staged to LDS (double buffer, 1 barrier/tap).
template<int NCH>
__global__ __launch_bounds__(256) void k_gemm27(
    const short* __restrict__ featA, const int* __restrict__ list,
    const int* __restrict__ idxg, int Dd,
    const short* __restrict__ Bs, short* __restrict__ out,
    const int* __restrict__ cntp,
    const float* __restrict__ scale, const float* __restrict__ shift)
{
    __shared__ short Blds[2][NCH*4*512];
    constexpr int NT = 27;
    const int ROWS = NCH * 32;
    int M = *cntp;
    int m0 = blockIdx.x * 64;
    if (m0 >= M) return;
    int tid = threadIdx.x;
    int wave = tid >> 6, lane = tid & 63;
    int m16 = lane & 15;
    int koff = (lane >> 4) * 8;

    int row = m0 + wave * 16 + m16;
    bool ok = row < M;
    int cell = ok ? list[row] : 0xFF0000;     // z=255 -> all taps OOB
    int z = cell >> 16, y = (cell >> 8) & 255, x = cell & 255;

    floatx4 acc[4] = {};
    f16x8 A[3][NCH];
    const f16x8 z8 = {0,0,0,0,0,0,0,0};

    auto stageB = [&](int j, int b){
        #pragma unroll
        for (int f = 0; f < NCH; ++f){
            int frag = wave * NCH + f;
            const short* g = Bs + (((long)j * NCH * 4 + frag) * 64 + lane) * 8;
            __builtin_amdgcn_global_load_lds((gas_t)g, (las_t)&Blds[b][frag * 512],
                                             16, 0, 0);
        }
    };
    auto getR = [&](int t)->int{
        int nz = z + t/9 - 1, ny = y + (t/3)%3 - 1, nx = x + t%3 - 1;
        int r = -1;
        if ((unsigned)nz < (unsigned)Dd && (unsigned)ny < H0_ && (unsigned)nx < W0_)
            r = idxg[(nz*H0_ + ny)*W0_ + nx];
        return r;
    };
    auto loadA = [&](f16x8* dst, int r){
        #pragma unroll
        for (int kc = 0; kc < NCH; ++kc)
            dst[kc] = (r >= 0) ? *(const f16x8*)(featA + (long)r*ROWS + koff + kc*32) : z8;
    };

    // prologue: r(0..2), A(0), A(1), B(0)
    int r0 = getR(0), r1 = getR(1), r2 = getR(2);
    stageB(0, 0);
    loadA(A[0], r0);
    loadA(A[1], r1);
    __syncthreads();

    #pragma unroll
    for (int t = 0; t < NT; ++t){
        if (t + 1 < NT) stageB(t + 1, (t + 1) & 1);
        if (t + 2 < NT) loadA(A[(t + 2) % 3], r2);
        int rn = (t + 3 < NT) ? getR(t + 3) : -1;
        if (__ballot(r0 >= 0) != 0){
            const short* Bb = Blds[t & 1];
            #pragma unroll
            for (int kc = 0; kc < NCH; ++kc){
                f16x8 b[4];
                #pragma unroll
                for (int nt = 0; nt < 4; ++nt)
                    b[nt] = *(const f16x8*)&Bb[((kc*4 + nt) * 64 + lane) * 8];
                f16x8 a = A[t % 3][kc];
                #pragma unroll
                for (int nt = 0; nt < 4; ++nt)
                    acc[nt] = __builtin_amdgcn_mfma_f32_16x16x32_f16(a, b[nt], acc[nt], 0, 0, 0);
            }
        }
        r0 = r1; r1 = r2; r2 = rn;
        __syncthreads();
    }

    // epilogue: C/D layout col = lane&15, row = (lane>>4)*4 + reg
    int n16 = lane & 15;
    int mb = m0 + wave * 16 + (lane >> 4) * 4;
    #pragma unroll
    for (int nt = 0; nt < 4; ++nt){
        int n = nt * 16 + n16;
        float sc = scale[n], sh = shift[n];
        #pragma unroll
        for (int r = 0; r < 4; ++r){
            int site = mb + r;
            if (site < M)
                out[(long)site*64 + n] = f2h(fmaxf(acc[nt][r] * sc + sh, 0.f));
        }
    }
}

// ---------------- 3-tap downsample gather-GEMM (inline parent idx), NCH=2 ----------------
template<bool FINAL>
__global__ __launch_bounds__(256) void k_gemmdn(
    const short* __restrict__ featA, const int* __restrict__ list,
    const int* __restrict__ idxg, int parentD,
    const short* __restrict__ Bs, short* __restrict__ out,
    const int* __restrict__ cntp,
    const float* __restrict__ scale, const float* __restrict__ shift,
    float* __restrict__ dout)
{
    __shared__ short Blds[2][2*4*512];
    constexpr int NT = 3;
    const int ROWS = 64;
    int M = *cntp;
    int m0 = blockIdx.x * 64;
    if (m0 >= M) return;
    int tid = threadIdx.x;
    int wave = tid >> 6, lane = tid & 63;
    int m16 = lane & 15;
    int koff = (lane >> 4) * 8;

    int row = m0 + wave * 16 + m16;
    bool ok = row < M;
    int cell = ok ? list[row] : 0;
    int d = ok ? (cell >> 16) : 300;          // 2*300 >= parentD -> r=-1
    int y = (cell >> 8) & 255, x = cell & 255;

    floatx4 acc[4] = {};
    f16x8 A[3][2];
    const f16x8 z8 = {0,0,0,0,0,0,0,0};

    auto stageB = [&](int j, int b){
        #pragma unroll
        for (int f = 0; f < 2; ++f){
            int frag = wave * 2 + f;
            const short* g = Bs + (((long)j * 8 + frag) * 64 + lane) * 8;
            __builtin_amdgcn_global_load_lds((gas_t)g, (las_t)&Blds[b][frag * 512],
                                             16, 0, 0);
        }
    };
    auto getR = [&](int t)->int{
        int pz = 2*d + t;
        int r = -1;
        if ((unsigned)pz < (unsigned)parentD)
            r = idxg[(pz*H0_ + y)*W0_ + x];
        return r;
    };
    auto loadA = [&](f16x8* dst, int r){
        #pragma unroll
        for (int kc = 0; kc < 2; ++kc)
            dst[kc] = (r >= 0) ? *(const f16x8*)(featA + (long)r*ROWS + koff + kc*32) : z8;
    };

    int r0 = getR(0), r1 = getR(1), r2 = getR(2);
    stageB(0, 0);
    loadA(A[0], r0);
    loadA(A[1], r1);
    __syncthreads();

    #pragma unroll
    for (int t = 0; t < NT; ++t){
        if (t + 1 < NT) stageB(t + 1, (t + 1) & 1);
        if (t + 2 < NT) loadA(A[(t + 2) % 3], r2);
        if (__ballot(r0 >= 0) != 0){
            const short* Bb = Blds[t & 1];
            #pragma unroll
            for (int kc = 0; kc < 2; ++kc){
                f16x8 b[4];
                #pragma unroll
                for (int nt = 0; nt < 4; ++nt)
                    b[nt] = *(const f16x8*)&Bb[((kc*4 + nt) * 64 + lane) * 8];
                f16x8 a = A[t % 3][kc];
                #pragma unroll
                for (int nt = 0; nt < 4; ++nt)
                    acc[nt] = __builtin_amdgcn_mfma_f32_16x16x32_f16(a, b[nt], acc[nt], 0, 0, 0);
            }
        }
        r0 = r1; r1 = r2; r2 = -1;
        __syncthreads();
    }

    int n16 = lane & 15;
    int mb = m0 + wave * 16 + (lane >> 4) * 4;
    #pragma unroll
    for (int nt = 0; nt < 4; ++nt){
        int n = nt * 16 + n16;
        float sc = scale[n], sh = shift[n];
        #pragma unroll
        for (int r = 0; r < 4; ++r){
            int site = mb + r;
            if (site < M){
                float yv = fmaxf(acc[nt][r] * sc + sh, 0.f);
                if (FINAL){
                    int c2 = list[site];
                    int dd = c2 >> 16, yy = (c2 >> 8) & 255, xx = c2 & 255;
                    dout[((n*4 + dd)*H0_ + yy)*W0_ + xx] = yv;
                } else {
                    out[(long)site*64 + n] = f2h(yv);
                }
            }
        }
    }
}

extern "C" void kernel_launch(void* const* d_in, const int* in_sizes, int n_in,
                              void* d_out, int out_size, void* d_ws, size_t ws_size,
                              hipStream_t stream){
    const float* vf   = (const float*)d_in[0];
    const int*   coors= (const int*)  d_in[1];
    const float* w1   = (const float*)d_in[3];
    const float* wd1  = (const float*)d_in[4];
    const float* w2   = (const float*)d_in[5];
    const float* w3   = (const float*)d_in[6];
    const float* wd2  = (const float*)d_in[7];
    const float* bng  = (const float*)d_in[8];
    const float* bnb  = (const float*)d_in[9];
    const float* bnm  = (const float*)d_in[10];
    const float* bnv  = (const float*)d_in[11];
    float* dout = (float*)d_out;

    char* ws = (char*)d_ws;
    size_t off = 0;
    auto alloc = [&](size_t bytes)->char* {
        char* p = ws + off;
        off += (bytes + 255) & ~(size_t)255;
        return p;
    };

    int*   counters = (int*)  alloc(256);                    // [0]=cnt0 [1]=cnt1 [2]=cnt2
    int*   cntg     = (int*)  alloc((size_t)NCELL0 * 4);
    int*   idx0     = (int*)  alloc((size_t)NCELL0 * 4);
    int*   idx1     = (int*)  alloc((size_t)NCELL1 * 4);
    int*   idx2     = (int*)  alloc((size_t)NCELL2 * 4);
    int*   list0    = (int*)  alloc((size_t)CAP0 * 4);
    int*   list1    = (int*)  alloc((size_t)CAP1 * 4);
    int*   list2    = (int*)  alloc((size_t)CAP2 * 4);
    float* feat0f   = (float*)alloc((size_t)CAP0 * 128 * 4);
    short* feat0h   = (short*)alloc((size_t)CAP0 * 128 * 2);  // L1 input, 128ch fp16
    short* feat1    = (short*)alloc((size_t)CAP0 * 64 * 2);   // 64ch fp16 activations
    short* featd1   = (short*)alloc((size_t)CAP1 * 64 * 2);
    short* feat2    = (short*)alloc((size_t)CAP1 * 64 * 2);
    short* feat3    = (short*)alloc((size_t)CAP1 * 64 * 2);
    short* B1  = (short*)alloc((size_t)3456 * 64 * 2);
    short* B2  = (short*)alloc((size_t)1728 * 64 * 2);
    short* B3  = (short*)alloc((size_t)1728 * 64 * 2);
    short* Bd1 = (short*)alloc((size_t)192 * 64 * 2);
    short* Bd2 = (short*)alloc((size_t)192 * 64 * 2);
    float* bnscale = (float*)alloc(5 * 64 * 4);
    float* bnshift = (float*)alloc(5 * 64 * 4);

    // ---- zero (ws/d_out poisoned 0xAA) ----
    hipMemsetAsync(counters, 0, 256 + (size_t)NCELL0 * 4, stream);
    hipMemsetAsync(feat0f, 0, (size_t)CAP0 * 128 * 4, stream);
    hipMemsetAsync(dout, 0, (size_t)out_size * 4, stream);

    // ---- constants + voxel count (one fused launch) ----
    k_prep<<<(PREP_TOT + 255)/256, 256, 0, stream>>>(w1, w2, w3, wd1, wd2,
        B1, B2, B3, Bd1, Bd2, bng, bnb, bnm, bnv, bnscale, bnshift, coors, cntg);

    // ---- sparse structure ----
    k_compact0<<<(NCELL0 + 255)/256, 256, 0, stream>>>(cntg, idx0, list0, counters + 0);
    k_scatter<<<(NV_*32 + 255)/256, 256, 0, stream>>>(vf, coors, cntg, idx0, feat0f);
    k_convert<<<(CAP0*16 + 255)/256, 256, 0, stream>>>(feat0f, feat0h, counters + 0);
    k_compact_dn<<<(NCELL1 + 255)/256, 256, 0, stream>>>(idx0, idx1, list1, counters + 1, NCELL1);
    k_compact_dn<<<(NCELL2 + 255)/256, 256, 0, stream>>>(idx1, idx2, list2, counters + 2, NCELL2);

    // ---- the five gather-GEMMs (fp16, M-tile 64, inline neighbor calc) ----
    k_gemm27<4><<<(CAP0+63)/64, 256, 0, stream>>>(feat0h, list0, idx0, D0_, B1, feat1,
        counters + 0, bnscale + 0,   bnshift + 0);
    k_gemmdn<false><<<(CAP1+63)/64, 256, 0, stream>>>(feat1, list1, idx0, D0_, Bd1, featd1,
        counters + 1, bnscale + 64,  bnshift + 64,  nullptr);
    k_gemm27<2><<<(CAP1+63)/64, 256, 0, stream>>>(featd1, list1, idx1, D1_, B2, feat2,
        counters + 1, bnscale + 128, bnshift + 128);
    k_gemm27<2><<<(CAP1+63)/64, 256, 0, stream>>>(feat2, list1, idx1, D1_, B3, feat3,
        counters + 1, bnscale + 192, bnshift + 192);
    k_gemmdn<true><<<(CAP2+63)/64, 256, 0, stream>>>(feat3, list2, idx1, D1_, Bd2, nullptr,
        counters + 2, bnscale + 256, bnshift + 256, dout);
}